// Round 4
// baseline (126.156 us; speedup 1.0000x reference)
//
#include <hip/hip_runtime.h>
#include <hip/hip_bf16.h>

#define NB 2
#define NH 16
#define SQ 2048
#define DH 64
#define LOG2E 1.44269504088896340736f

typedef short bf16x8 __attribute__((ext_vector_type(8)));
typedef float f32x16 __attribute__((ext_vector_type(16)));
typedef unsigned u32x2 __attribute__((ext_vector_type(2)));

// 3-bit granule swizzle: bank-spreads 16B granules (G4 / T2)
#define SW(r) ((((r) & 7) ^ (((r) >> 3) & 7)))

__device__ __forceinline__ unsigned cvtpk(float a, float b) {
  unsigned r;
  asm("v_cvt_pk_bf16_f32 %0, %1, %2" : "=v"(r) : "v"(a), "v"(b));
  return r;
}
__device__ __forceinline__ float uasf(unsigned u) {
  union { unsigned u; float f; } x; x.u = u; return x.f;
}
__device__ __forceinline__ float exp2asm(float x) {  // 2^x
  float r;
  asm("v_exp_f32 %0, %1" : "=v"(r) : "v"(x));
  return r;
}
__device__ __forceinline__ void gll16(const void* g, void* l) {
  __builtin_amdgcn_global_load_lds(
      (const __attribute__((address_space(1))) void*)g,
      (__attribute__((address_space(3))) void*)l, 16, 0, 0);
}

union AFrag { unsigned u[4]; bf16x8 v; };

// ---- pre-pass: K -> bf16 hi/lo (same layout), V -> V^T bf16 [bh][d][S]
__global__ __launch_bounds__(256) void prep_kv(
    const float* __restrict__ k, const float* __restrict__ v,
    short* __restrict__ kh, short* __restrict__ kl, short* __restrict__ vt) {
  __shared__ short vls[64][72];
  const int tid = threadIdx.x;
  const int bh = blockIdx.y;
  const int s0 = blockIdx.x * 64;
  const size_t kbase = ((size_t)bh * SQ + s0) * DH;
#pragma unroll
  for (int i = 0; i < 4; ++i) {
    int idx = i * 256 + tid;
    int row = idx >> 4;
    int c4 = (idx & 15) << 2;
    float4 kk = *(const float4*)(k + kbase + row * DH + c4);
    unsigned h01 = cvtpk(kk.x, kk.y), h23 = cvtpk(kk.z, kk.w);
    unsigned l01 = cvtpk(kk.x - uasf(h01 << 16), kk.y - uasf(h01 & 0xffff0000u));
    unsigned l23 = cvtpk(kk.z - uasf(h23 << 16), kk.w - uasf(h23 & 0xffff0000u));
    *(u32x2*)(kh + kbase + row * DH + c4) = (u32x2){h01, h23};
    *(u32x2*)(kl + kbase + row * DH + c4) = (u32x2){l01, l23};
    float4 vv = *(const float4*)(v + kbase + row * DH + c4);
    unsigned v01 = cvtpk(vv.x, vv.y), v23 = cvtpk(vv.z, vv.w);
    vls[c4 + 0][row] = (short)(v01 & 0xffffu);
    vls[c4 + 1][row] = (short)(v01 >> 16);
    vls[c4 + 2][row] = (short)(v23 & 0xffffu);
    vls[c4 + 3][row] = (short)(v23 >> 16);
  }
  __syncthreads();
#pragma unroll
  for (int i = 0; i < 2; ++i) {
    int idx = i * 256 + tid;
    int d = idx >> 3;
    int ch = (idx & 7) * 8;
    union { short s[8]; bf16x8 v; } t;
#pragma unroll
    for (int j = 0; j < 8; ++j) t.s[j] = vls[d][ch + j];
    *(bf16x8*)(vt + ((size_t)bh * DH + d) * SQ + s0 + ch) = t.v;
  }
}

// ---- main: 4 waves x 64 q-rows = 256 rows/block, 1 block/CU, 4-buf pipeline
__global__ __launch_bounds__(256, 1) void attn_causal_fwd(
    const float* __restrict__ q, const short* __restrict__ kh,
    const short* __restrict__ kl, const short* __restrict__ vt,
    float* __restrict__ out) {
  __shared__ short lds[4][3][64][64];  // [buf][kh,kl,vt][row][col] = 96 KB

  const int tid = threadIdx.x;
  const int wave = tid >> 6;
  const int lane = tid & 63;
  const int q31 = lane & 31;
  const int h5 = lane >> 5;

  // 256 blocks: XCD gets 4 heads (3MB K/V fits L2); heavy groups dispatch first
  const int lid = (int)blockIdx.y * (int)gridDim.x + (int)blockIdx.x;
  const int bh = 4 * (lid & 7) + ((lid >> 3) & 3);
  const int g = 7 - (lid >> 5);
  const int qbase = g * 256;
  const size_t base = (size_t)bh * SQ * DH;
  const int qrow_w = qbase + wave * 64;  // wave's 64 q-rows

  // ---- Q fragments (2 row-groups), scaled by log2e, bf16 hi/lo split
  bf16x8 qh[2][4], ql[2][4];
#pragma unroll
  for (int rg = 0; rg < 2; ++rg) {
#pragma unroll
    for (int ks = 0; ks < 4; ++ks) {
      const float* qp =
          q + base + (size_t)(qrow_w + rg * 32 + q31) * DH + ks * 16 + h5 * 8;
      float4 a = *(const float4*)qp;
      float4 b = *(const float4*)(qp + 4);
      a.x *= LOG2E; a.y *= LOG2E; a.z *= LOG2E; a.w *= LOG2E;
      b.x *= LOG2E; b.y *= LOG2E; b.z *= LOG2E; b.w *= LOG2E;
      unsigned h0 = cvtpk(a.x, a.y), h1 = cvtpk(a.z, a.w);
      unsigned h2 = cvtpk(b.x, b.y), h3 = cvtpk(b.z, b.w);
      unsigned l0 = cvtpk(a.x - uasf(h0 << 16), a.y - uasf(h0 & 0xffff0000u));
      unsigned l1 = cvtpk(a.z - uasf(h1 << 16), a.w - uasf(h1 & 0xffff0000u));
      unsigned l2 = cvtpk(b.x - uasf(h2 << 16), b.y - uasf(h2 & 0xffff0000u));
      unsigned l3 = cvtpk(b.z - uasf(h3 << 16), b.w - uasf(h3 & 0xffff0000u));
      AFrag fh; fh.u[0] = h0; fh.u[1] = h1; fh.u[2] = h2; fh.u[3] = h3;
      qh[rg][ks] = fh.v;
      AFrag fl; fl.u[0] = l0; fl.u[1] = l1; fl.u[2] = l2; fl.u[3] = l3;
      ql[rg][ks] = fl.v;
    }
  }
  __builtin_amdgcn_sched_barrier(0);  // Q loads retire before stage accounting

  // ---- staging addresses (pre-swizzled global sources, linear LDS dests)
  const int l8 = lane >> 3, s8 = lane & 7;
  const char* khB = (const char*)(kh + base);
  const char* klB = (const char*)(kl + base);
  const char* vtB = (const char*)(vt + (size_t)bh * DH * SQ);
  int kOffA[2], vOffA[2];
#pragma unroll
  for (int j = 0; j < 2; ++j) {
    int cj = wave * 2 + j;
    int r = cj * 8 + l8;
    int sw = (s8 ^ l8 ^ cj) * 16;
    kOffA[j] = r * 128 + sw;
    vOffA[j] = r * 4096 + sw;
  }
#define STAGE(tt, nb)                                                   \
  do {                                                                  \
    size_t kt_ = (size_t)(tt)*8192;                                     \
    size_t vt_ = (size_t)(tt)*128;                                      \
    _Pragma("unroll") for (int j = 0; j < 2; ++j) {                     \
      int cj = wave * 2 + j;                                            \
      gll16(khB + kt_ + kOffA[j], &lds[nb][0][cj * 8][0]);              \
      gll16(klB + kt_ + kOffA[j], &lds[nb][1][cj * 8][0]);              \
      gll16(vtB + vt_ + vOffA[j], &lds[nb][2][cj * 8][0]);              \
    }                                                                   \
  } while (0)

  const int ntiles = qbase / 64 + 4;
  STAGE(0, 0);
  STAGE(1, 1);

  f32x16 o[2][2];
#pragma unroll
  for (int rg = 0; rg < 2; ++rg)
#pragma unroll
    for (int dt = 0; dt < 2; ++dt)
#pragma unroll
      for (int r = 0; r < 16; ++r) o[rg][dt][r] = 0.f;
  float m_run[2] = {-1e30f, -1e30f}, l_run[2] = {0.f, 0.f};

  for (int t = 0; t < ntiles; ++t) {
    const int kv0 = t * 64;
    if (t + 2 < ntiles) {
      STAGE(t + 2, (t + 2) & 3);
      asm volatile("s_waitcnt vmcnt(12)" ::: "memory");  // tile t landed; t+1,t+2 in flight
    } else if (t + 1 < ntiles) {
      asm volatile("s_waitcnt vmcnt(6)" ::: "memory");
    } else {
      asm volatile("s_waitcnt vmcnt(0)" ::: "memory");
    }
    __builtin_amdgcn_sched_barrier(0);
    __builtin_amdgcn_s_barrier();
    __builtin_amdgcn_sched_barrier(0);

    const int buf = t & 3;
    const short(*khs)[64] = (const short(*)[64])lds[buf][0];
    const short(*kls)[64] = (const short(*)[64])lds[buf][1];
    const short(*vts)[64] = (const short(*)[64])lds[buf][2];

    if (kv0 <= qrow_w + 63) {
      // activity per (rowgroup, kt-half)
      bool act[2][2];
#pragma unroll
      for (int rg = 0; rg < 2; ++rg)
#pragma unroll
        for (int kt = 0; kt < 2; ++kt)
          act[rg][kt] = (kv0 + kt * 32) <= (qrow_w + rg * 32 + 31);

      // ---- S^T = K·Q (swapped): lane-local P rows; 3-term hi/lo; 2 rowgroups
      f32x16 sa[2][2];
#pragma unroll
      for (int kt = 0; kt < 2; ++kt) {
        if (act[1][kt]) {
          const int rr = kt * 32 + q31;
          const int swr = SW(rr);
#pragma unroll
          for (int r = 0; r < 16; ++r) { sa[0][kt][r] = 0.f; sa[1][kt][r] = 0.f; }
#pragma unroll
          for (int ks = 0; ks < 4; ++ks) {
            const int gg = ((ks * 2 + h5) ^ swr) * 8;
            bf16x8 ah = *(const bf16x8*)&khs[rr][gg];
            bf16x8 al = *(const bf16x8*)&kls[rr][gg];
            if (act[0][kt]) {
              sa[0][kt] = __builtin_amdgcn_mfma_f32_32x32x16_bf16(ah, qh[0][ks], sa[0][kt], 0, 0, 0);
              sa[0][kt] = __builtin_amdgcn_mfma_f32_32x32x16_bf16(al, qh[0][ks], sa[0][kt], 0, 0, 0);
              sa[0][kt] = __builtin_amdgcn_mfma_f32_32x32x16_bf16(ah, ql[0][ks], sa[0][kt], 0, 0, 0);
            }
            sa[1][kt] = __builtin_amdgcn_mfma_f32_32x32x16_bf16(ah, qh[1][ks], sa[1][kt], 0, 0, 0);
            sa[1][kt] = __builtin_amdgcn_mfma_f32_32x32x16_bf16(al, qh[1][ks], sa[1][kt], 0, 0, 0);
            sa[1][kt] = __builtin_amdgcn_mfma_f32_32x32x16_bf16(ah, ql[1][ks], sa[1][kt], 0, 0, 0);
          }
        }
      }
      // ---- causal mask on diagonal halves
#pragma unroll
      for (int rg = 0; rg < 2; ++rg) {
#pragma unroll
        for (int kt = 0; kt < 2; ++kt) {
          if (act[rg][kt] && !(kv0 + kt * 32 + 31 <= qrow_w + rg * 32)) {
            const int qg = qrow_w + rg * 32 + q31;
#pragma unroll
            for (int r = 0; r < 16; ++r) {
              int kvv = kv0 + kt * 32 + (r & 3) + 8 * (r >> 2) + 4 * h5;
              sa[rg][kt][r] = (kvv <= qg) ? sa[rg][kt][r] : -1e30f;
            }
          }
        }
      }
      // ---- online softmax per rowgroup (log2 domain), defer-rescale THR=8
      unsigned cpk[2][2][8];
#pragma unroll
      for (int rg = 0; rg < 2; ++rg) {
        if (act[rg][0]) {
          float m16 = -1e30f;
#pragma unroll
          for (int kt = 0; kt < 2; ++kt)
            if (act[rg][kt])
#pragma unroll
              for (int r = 0; r < 16; ++r) m16 = fmaxf(m16, sa[rg][kt][r]);
          float mm = fmaxf(m16, __shfl_xor(m16, 32));
          if (!__all(mm - m_run[rg] <= 8.0f)) {
            float mnew = fmaxf(m_run[rg], mm);
            float sc = exp2asm(m_run[rg] - mnew);
            l_run[rg] *= sc;
            m_run[rg] = mnew;
#pragma unroll
            for (int r = 0; r < 16; ++r) {
              float s_r = __shfl(sc, (r & 3) + 8 * (r >> 2) + 4 * h5);
              o[rg][0][r] *= s_r;
              o[rg][1][r] *= s_r;
            }
          }
          float rs = 0.f;
#pragma unroll
          for (int kt = 0; kt < 2; ++kt) {
            if (act[rg][kt]) {
#pragma unroll
              for (int r = 0; r < 16; ++r) {
                float e = exp2asm(sa[rg][kt][r] - m_run[rg]);
                sa[rg][kt][r] = e;
                rs += e;
              }
#pragma unroll
              for (int i = 0; i < 8; ++i)
                cpk[rg][kt][i] = cvtpk(sa[rg][kt][2 * i], sa[rg][kt][2 * i + 1]);
            }
          }
          rs += __shfl_xor(rs, 32);
          l_run[rg] += rs;
        }
      }
      // ---- O += P·V : A-frags in-register via half-swap (T12); B shared per s
#pragma unroll
      for (int s = 0; s < 4; ++s) {
        const int kt = s >> 1, s1 = s & 1;
        if (act[1][kt]) {
          const int gg0 = ((s * 2 + h5) ^ SW(q31)) * 8;
          bf16x8 b0 = *(const bf16x8*)&vts[q31][gg0];
          const int gg1 = ((s * 2 + h5) ^ SW(32 + q31)) * 8;
          bf16x8 b1 = *(const bf16x8*)&vts[32 + q31][gg1];
#pragma unroll
          for (int rg = 0; rg < 2; ++rg) {
            if (act[rg][kt]) {
              unsigned P0 = cpk[rg][kt][s1 * 4 + 0], P1 = cpk[rg][kt][s1 * 4 + 1];
              unsigned Q0 = cpk[rg][kt][s1 * 4 + 2], Q1 = cpk[rg][kt][s1 * 4 + 3];
              unsigned X0 = h5 ? Q0 : P0, Z0 = h5 ? P0 : Q0;
              unsigned X1 = h5 ? Q1 : P1, Z1 = h5 ? P1 : Q1;
              unsigned c0 = (unsigned)__shfl_xor((int)Z0, 32);
              unsigned c1 = (unsigned)__shfl_xor((int)Z1, 32);
              AFrag af;
              af.u[0] = h5 ? c0 : X0;
              af.u[1] = h5 ? c1 : X1;
              af.u[2] = h5 ? X0 : c0;
              af.u[3] = h5 ? X1 : c1;
              o[rg][0] = __builtin_amdgcn_mfma_f32_32x32x16_bf16(af.v, b0, o[rg][0], 0, 0, 0);
              o[rg][1] = __builtin_amdgcn_mfma_f32_32x32x16_bf16(af.v, b1, o[rg][1], 0, 0, 0);
            }
          }
        }
      }
    }
  }

  // ---- epilogue: O / l
#pragma unroll
  for (int rg = 0; rg < 2; ++rg) {
    float inv = 1.0f / l_run[rg];
#pragma unroll
    for (int r = 0; r < 16; ++r) {
      int qr = (r & 3) + 8 * (r >> 2) + 4 * h5;
      float ss = __shfl(inv, qr);
      float* op = out + base + (size_t)(qrow_w + rg * 32 + qr) * DH + q31;
      op[0] = o[rg][0][r] * ss;
      op[32] = o[rg][1][r] * ss;
    }
  }
}

extern "C" void kernel_launch(void* const* d_in, const int* in_sizes, int n_in,
                              void* d_out, int out_size, void* d_ws, size_t ws_size,
                              hipStream_t stream) {
  const float* q = (const float*)d_in[0];
  const float* k = (const float*)d_in[1];
  const float* v = (const float*)d_in[2];
  // d_in[3] (mask) is tril(ones) by construction -> applied analytically.
  float* out = (float*)d_out;
  const size_t elems = (size_t)NB * NH * SQ * DH;  // 4,194,304
  short* khs = (short*)d_ws;
  short* kls = khs + elems;
  short* vts = kls + elems;

  hipLaunchKernelGGL(prep_kv, dim3(SQ / 64, NB * NH), dim3(256), 0, stream,
                     k, v, khs, kls, vts);
  hipLaunchKernelGGL(attn_causal_fwd, dim3(8, NB * NH), dim3(256), 0, stream,
                     q, khs, kls, vts, out);
}

// Round 5
// 70.538 us; speedup vs baseline: 1.7885x; 1.7885x over previous
//
#include <hip/hip_runtime.h>
#include <hip/hip_bf16.h>

#define NB 2
#define NH 16
#define SQ 2048
#define DH 64
#define LOG2E 1.44269504088896340736f

typedef short bf16x8 __attribute__((ext_vector_type(8)));
typedef float f32x16 __attribute__((ext_vector_type(16)));
typedef unsigned u32x2 __attribute__((ext_vector_type(2)));

__device__ __forceinline__ unsigned cvtpk(float a, float b) {
  unsigned r;
  asm("v_cvt_pk_bf16_f32 %0, %1, %2" : "=v"(r) : "v"(a), "v"(b));
  return r;
}
__device__ __forceinline__ float uasf(unsigned u) {
  union { unsigned u; float f; } x; x.u = u; return x.f;
}
__device__ __forceinline__ float exp2asm(float x) {  // 2^x
  float r;
  asm("v_exp_f32 %0, %1" : "=v"(r) : "v"(x));
  return r;
}

union AFrag { unsigned u[4]; bf16x8 v; };

// ---- pre-pass: write K (bf16 hi/lo) and V^T in FRAGMENT-MAJOR layout.
// Granule = 64 lanes x 16B, exactly one MFMA operand for a whole wave:
//   K  granule (t,kt,ks): lane l <- K[t*64+kt*32+(l&31)][ks*16+(l>>5)*8 +0..7]
//   V  granule (t,s,pr) : lane l <- V^T[pr*32+(l&31)][s*16+(l>>5)*8 +0..7]
// Per (head,tile): 4096 shorts (8KB) per array; per head: 32 tiles = 256KB.
__global__ __launch_bounds__(256) void prep_kv(
    const float* __restrict__ k, const float* __restrict__ v,
    short* __restrict__ khF, short* __restrict__ klF, short* __restrict__ vtF) {
  __shared__ short khls[64][72];
  __shared__ short klls[64][72];
  __shared__ short vls[64][72];  // V^T: vls[d][kv]
  const int tid = threadIdx.x;
  const int t = blockIdx.x;   // kv tile (64 rows)
  const int bh = blockIdx.y;
  const size_t inbase = ((size_t)bh * SQ + t * 64) * DH;
#pragma unroll
  for (int i = 0; i < 4; ++i) {
    int idx = i * 256 + tid;
    int row = idx >> 4;
    int c4 = (idx & 15) << 2;
    float4 kk = *(const float4*)(k + inbase + row * DH + c4);
    unsigned h01 = cvtpk(kk.x, kk.y), h23 = cvtpk(kk.z, kk.w);
    unsigned l01 = cvtpk(kk.x - uasf(h01 << 16), kk.y - uasf(h01 & 0xffff0000u));
    unsigned l23 = cvtpk(kk.z - uasf(h23 << 16), kk.w - uasf(h23 & 0xffff0000u));
    *(u32x2*)&khls[row][c4] = (u32x2){h01, h23};
    *(u32x2*)&klls[row][c4] = (u32x2){l01, l23};
    float4 vv = *(const float4*)(v + inbase + row * DH + c4);
    unsigned v01 = cvtpk(vv.x, vv.y), v23 = cvtpk(vv.z, vv.w);
    vls[c4 + 0][row] = (short)(v01 & 0xffffu);
    vls[c4 + 1][row] = (short)(v01 >> 16);
    vls[c4 + 2][row] = (short)(v23 & 0xffffu);
    vls[c4 + 3][row] = (short)(v23 >> 16);
  }
  __syncthreads();
  const size_t ob = ((size_t)bh * 32 + t) * 4096;  // shorts
#pragma unroll
  for (int it = 0; it < 2; ++it) {
    int g = it * 256 + tid;  // 0..511
    // K granules: g = kt*256 + ks*64 + l
    int kt = g >> 8, ks = (g >> 6) & 3, l = g & 63;
    bf16x8 hv = *(const bf16x8*)&khls[kt * 32 + (l & 31)][ks * 16 + (l >> 5) * 8];
    bf16x8 lv = *(const bf16x8*)&klls[kt * 32 + (l & 31)][ks * 16 + (l >> 5) * 8];
    *(bf16x8*)(khF + ob + (size_t)g * 8) = hv;
    *(bf16x8*)(klF + ob + (size_t)g * 8) = lv;
    // V granules: g = s*128 + pr*64 + l
    int s = g >> 7, pr = (g >> 6) & 1;
    bf16x8 vv8 = *(const bf16x8*)&vls[pr * 32 + (l & 31)][s * 16 + (l >> 5) * 8];
    *(bf16x8*)(vtF + ob + (size_t)g * 8) = vv8;
  }
}

// ---- main: 1 wave per block, 32 q-rows per wave, NO LDS, NO barriers.
// Operands load coalesced from frag-major arrays (L2-resident per XCD).
__global__ __launch_bounds__(64, 2) void attn_causal_fwd(
    const float* __restrict__ q, const short* __restrict__ khF,
    const short* __restrict__ klF, const short* __restrict__ vtF,
    float* __restrict__ out) {
  const int lane = threadIdx.x;
  const int q31 = lane & 31;
  const int h5 = lane >> 5;

  // lid&31 = head (head%8 = XCD -> 4 heads/XCD, 3MB frag data fits 4MB L2);
  // lid>>5 = q-position, heavy (high qb) first for LPT balance.
  const int lid = (int)blockIdx.x;
  const int bh = lid & 31;
  const int qw = lid >> 5;           // 0..63
  const int qb = 15 - (qw >> 2);
  const int qrow_w = qb * 128 + (qw & 3) * 32;  // wave's 32 q-rows
  const size_t base = (size_t)bh * SQ * DH;
  const short* khB = khF + (size_t)bh * 131072;
  const short* klB = klF + (size_t)bh * 131072;
  const short* vtB = vtF + (size_t)bh * 131072;

  // ---- Q fragments scaled by log2e, bf16 hi/lo split
  bf16x8 qh[4], ql[4];
#pragma unroll
  for (int ks = 0; ks < 4; ++ks) {
    const float* qp = q + base + (size_t)(qrow_w + q31) * DH + ks * 16 + h5 * 8;
    float4 a = *(const float4*)qp;
    float4 b = *(const float4*)(qp + 4);
    a.x *= LOG2E; a.y *= LOG2E; a.z *= LOG2E; a.w *= LOG2E;
    b.x *= LOG2E; b.y *= LOG2E; b.z *= LOG2E; b.w *= LOG2E;
    unsigned h0 = cvtpk(a.x, a.y), h1 = cvtpk(a.z, a.w);
    unsigned h2 = cvtpk(b.x, b.y), h3 = cvtpk(b.z, b.w);
    unsigned l0 = cvtpk(a.x - uasf(h0 << 16), a.y - uasf(h0 & 0xffff0000u));
    unsigned l1 = cvtpk(a.z - uasf(h1 << 16), a.w - uasf(h1 & 0xffff0000u));
    unsigned l2 = cvtpk(b.x - uasf(h2 << 16), b.y - uasf(h2 & 0xffff0000u));
    unsigned l3 = cvtpk(b.z - uasf(h3 << 16), b.w - uasf(h3 & 0xffff0000u));
    AFrag fh; fh.u[0] = h0; fh.u[1] = h1; fh.u[2] = h2; fh.u[3] = h3; qh[ks] = fh.v;
    AFrag fl; fl.u[0] = l0; fl.u[1] = l1; fl.u[2] = l2; fl.u[3] = l3; ql[ks] = fl.v;
  }

  f32x16 o0, o1;
#pragma unroll
  for (int r = 0; r < 16; ++r) { o0[r] = 0.f; o1[r] = 0.f; }
  float m_run = -1e30f, l_run = 0.f;

  const int ntiles = qrow_w / 64 + 1;
  for (int t = 0; t < ntiles; ++t) {
    const int kv0 = t * 64;
    const int nk = (kv0 + 32 <= qrow_w + 31) ? 2 : 1;
    const size_t tb = (size_t)t * 4096;  // shorts

    // ---- coalesced operand loads (64 lanes x 16B = one 1KB transaction each)
    bf16x8 ah[2][4], al[2][4], bv[4][2];
#pragma unroll
    for (int kt = 0; kt < 2; ++kt) {
      if (kt < nk) {
#pragma unroll
        for (int ks = 0; ks < 4; ++ks) {
          ah[kt][ks] = *(const bf16x8*)(khB + tb + (kt * 4 + ks) * 512 + lane * 8);
          al[kt][ks] = *(const bf16x8*)(klB + tb + (kt * 4 + ks) * 512 + lane * 8);
        }
      }
    }
#pragma unroll
    for (int s = 0; s < 4; ++s) {
      if ((s >> 1) < nk) {
#pragma unroll
        for (int pr = 0; pr < 2; ++pr)
          bv[s][pr] = *(const bf16x8*)(vtB + tb + (s * 2 + pr) * 512 + lane * 8);
      }
    }

    // ---- S^T = K·Q (swapped): lane-local P rows; 3-term hi/lo
    f32x16 sa[2];
    __builtin_amdgcn_s_setprio(1);
#pragma unroll
    for (int kt = 0; kt < 2; ++kt) {
      if (kt < nk) {
#pragma unroll
        for (int r = 0; r < 16; ++r) sa[kt][r] = 0.f;
#pragma unroll
        for (int ks = 0; ks < 4; ++ks) {
          sa[kt] = __builtin_amdgcn_mfma_f32_32x32x16_bf16(ah[kt][ks], qh[ks], sa[kt], 0, 0, 0);
          sa[kt] = __builtin_amdgcn_mfma_f32_32x32x16_bf16(al[kt][ks], qh[ks], sa[kt], 0, 0, 0);
          sa[kt] = __builtin_amdgcn_mfma_f32_32x32x16_bf16(ah[kt][ks], ql[ks], sa[kt], 0, 0, 0);
        }
      }
    }
    __builtin_amdgcn_s_setprio(0);

    // ---- causal mask on diagonal halves only
#pragma unroll
    for (int kt = 0; kt < 2; ++kt) {
      if (kt < nk && !(kv0 + kt * 32 + 31 <= qrow_w)) {
        const int qg = qrow_w + q31;
#pragma unroll
        for (int r = 0; r < 16; ++r) {
          int kvv = kv0 + kt * 32 + (r & 3) + 8 * (r >> 2) + 4 * h5;
          sa[kt][r] = (kvv <= qg) ? sa[kt][r] : -1e30f;
        }
      }
    }

    // ---- online softmax (log2 domain), defer-rescale THR=8
    float m16 = -1e30f;
#pragma unroll
    for (int kt = 0; kt < 2; ++kt)
      if (kt < nk)
#pragma unroll
        for (int r = 0; r < 16; ++r) m16 = fmaxf(m16, sa[kt][r]);
    float mm = fmaxf(m16, __shfl_xor(m16, 32));
    if (!__all(mm - m_run <= 8.0f)) {
      float mnew = fmaxf(m_run, mm);
      float sc = exp2asm(m_run - mnew);
      l_run *= sc;
      m_run = mnew;
#pragma unroll
      for (int r = 0; r < 16; ++r) {
        float s_r = __shfl(sc, (r & 3) + 8 * (r >> 2) + 4 * h5);
        o0[r] *= s_r;
        o1[r] *= s_r;
      }
    }
    float rs = 0.f;
    unsigned cpk[2][8];
#pragma unroll
    for (int kt = 0; kt < 2; ++kt) {
      if (kt < nk) {
#pragma unroll
        for (int r = 0; r < 16; ++r) {
          float e = exp2asm(sa[kt][r] - m_run);
          sa[kt][r] = e;
          rs += e;
        }
#pragma unroll
        for (int i = 0; i < 8; ++i)
          cpk[kt][i] = cvtpk(sa[kt][2 * i], sa[kt][2 * i + 1]);
      }
    }
    rs += __shfl_xor(rs, 32);
    l_run += rs;

    // ---- O += P·V : A-frags in-register via half-swap (T12)
    __builtin_amdgcn_s_setprio(1);
#pragma unroll
    for (int s = 0; s < 4; ++s) {
      if ((s >> 1) < nk) {
        const int kt = s >> 1, s1 = s & 1;
        unsigned P0 = cpk[kt][s1 * 4 + 0], P1 = cpk[kt][s1 * 4 + 1];
        unsigned Q0 = cpk[kt][s1 * 4 + 2], Q1 = cpk[kt][s1 * 4 + 3];
        unsigned X0 = h5 ? Q0 : P0, Z0 = h5 ? P0 : Q0;
        unsigned X1 = h5 ? Q1 : P1, Z1 = h5 ? P1 : Q1;
        unsigned c0 = (unsigned)__shfl_xor((int)Z0, 32);
        unsigned c1 = (unsigned)__shfl_xor((int)Z1, 32);
        AFrag af;
        af.u[0] = h5 ? c0 : X0;
        af.u[1] = h5 ? c1 : X1;
        af.u[2] = h5 ? X0 : c0;
        af.u[3] = h5 ? X1 : c1;
        o0 = __builtin_amdgcn_mfma_f32_32x32x16_bf16(af.v, bv[s][0], o0, 0, 0, 0);
        o1 = __builtin_amdgcn_mfma_f32_32x32x16_bf16(af.v, bv[s][1], o1, 0, 0, 0);
      }
    }
    __builtin_amdgcn_s_setprio(0);
  }

  // ---- epilogue: O / l
  float inv = 1.0f / l_run;
#pragma unroll
  for (int r = 0; r < 16; ++r) {
    int qr = (r & 3) + 8 * (r >> 2) + 4 * h5;
    float ss = __shfl(inv, qr);
    float* op = out + base + (size_t)(qrow_w + qr) * DH + q31;
    op[0] = o0[r] * ss;
    op[32] = o1[r] * ss;
  }
}

extern "C" void kernel_launch(void* const* d_in, const int* in_sizes, int n_in,
                              void* d_out, int out_size, void* d_ws, size_t ws_size,
                              hipStream_t stream) {
  const float* q = (const float*)d_in[0];
  const float* k = (const float*)d_in[1];
  const float* v = (const float*)d_in[2];
  // d_in[3] (mask) is tril(ones) by construction -> applied analytically.
  float* out = (float*)d_out;
  const size_t elems = (size_t)NB * NH * SQ * DH;  // 4,194,304 shorts per array
  short* khF = (short*)d_ws;
  short* klF = khF + elems;
  short* vtF = klF + elems;

  hipLaunchKernelGGL(prep_kv, dim3(SQ / 64, NB * NH), dim3(256), 0, stream,
                     k, v, khF, klF, vtF);
  hipLaunchKernelGGL(attn_causal_fwd, dim3(NB * NH * 64), dim3(64), 0, stream,
                     q, khF, klF, vtF, out);
}

// Round 6
// 69.714 us; speedup vs baseline: 1.8096x; 1.0118x over previous
//
#include <hip/hip_runtime.h>
#include <hip/hip_bf16.h>

#define NB 2
#define NH 16
#define SQ 2048
#define DH 64
#define LOG2E 1.44269504088896340736f

typedef short bf16x8 __attribute__((ext_vector_type(8)));
typedef float f32x16 __attribute__((ext_vector_type(16)));
typedef unsigned u32x2 __attribute__((ext_vector_type(2)));

__device__ __forceinline__ unsigned cvtpk(float a, float b) {
  unsigned r;
  asm("v_cvt_pk_bf16_f32 %0, %1, %2" : "=v"(r) : "v"(a), "v"(b));
  return r;
}
__device__ __forceinline__ float uasf(unsigned u) {
  union { unsigned u; float f; } x; x.u = u; return x.f;
}
__device__ __forceinline__ float exp2asm(float x) {  // 2^x
  float r;
  asm("v_exp_f32 %0, %1" : "=v"(r) : "v"(x));
  return r;
}
__device__ __forceinline__ void gll16(const void* g, void* l) {
  __builtin_amdgcn_global_load_lds(
      (const __attribute__((address_space(1))) void*)g,
      (__attribute__((address_space(3))) void*)l, 16, 0, 0);
}

union AFrag { unsigned u[4]; bf16x8 v; };

// ---- pre-pass: per (head, 64-kv tile) a 24KB FRAG-MAJOR chunk:
//   [K-hi 8KB | K-lo 8KB | V^T 8KB], each = 8 granules of 1KB,
//   granule = 64 lanes x 16B = exactly one wave MFMA operand.
//   K granule (kt,ks): lane l <- K[kt*32+(l&31)][ks*16+(l>>5)*8 +0..7]
//   V granule (s,pr) : lane l <- V^T[pr*32+(l&31)][s*16+(l>>5)*8 +0..7]
__global__ __launch_bounds__(256) void prep_kv(
    const float* __restrict__ k, const float* __restrict__ v,
    short* __restrict__ kvF) {
  __shared__ short khls[64][72];
  __shared__ short klls[64][72];
  __shared__ short vls[64][72];  // V^T: vls[d][kv]
  const int tid = threadIdx.x;
  const int t = blockIdx.x;   // kv tile (64 rows)
  const int bh = blockIdx.y;
  const size_t inbase = ((size_t)bh * SQ + t * 64) * DH;
#pragma unroll
  for (int i = 0; i < 4; ++i) {
    int idx = i * 256 + tid;
    int row = idx >> 4;
    int c4 = (idx & 15) << 2;
    float4 kk = *(const float4*)(k + inbase + row * DH + c4);
    unsigned h01 = cvtpk(kk.x, kk.y), h23 = cvtpk(kk.z, kk.w);
    unsigned l01 = cvtpk(kk.x - uasf(h01 << 16), kk.y - uasf(h01 & 0xffff0000u));
    unsigned l23 = cvtpk(kk.z - uasf(h23 << 16), kk.w - uasf(h23 & 0xffff0000u));
    *(u32x2*)&khls[row][c4] = (u32x2){h01, h23};
    *(u32x2*)&klls[row][c4] = (u32x2){l01, l23};
    float4 vv = *(const float4*)(v + inbase + row * DH + c4);
    unsigned v01 = cvtpk(vv.x, vv.y), v23 = cvtpk(vv.z, vv.w);
    vls[c4 + 0][row] = (short)(v01 & 0xffffu);
    vls[c4 + 1][row] = (short)(v01 >> 16);
    vls[c4 + 2][row] = (short)(v23 & 0xffffu);
    vls[c4 + 3][row] = (short)(v23 >> 16);
  }
  __syncthreads();
  const size_t ob = ((size_t)bh * 32 + t) * 12288;  // shorts (24KB chunks)
#pragma unroll
  for (int it = 0; it < 2; ++it) {
    int g = it * 256 + tid;  // 0..511: granule g>>6, lane g&63
    int kt = g >> 8, ks = (g >> 6) & 3, l = g & 63;
    bf16x8 hv = *(const bf16x8*)&khls[kt * 32 + (l & 31)][ks * 16 + (l >> 5) * 8];
    bf16x8 lv = *(const bf16x8*)&klls[kt * 32 + (l & 31)][ks * 16 + (l >> 5) * 8];
    *(bf16x8*)(kvF + ob + (size_t)g * 8) = hv;
    *(bf16x8*)(kvF + ob + 4096 + (size_t)g * 8) = lv;
    int s = g >> 7, pr = (g >> 6) & 1;
    bf16x8 vv8 = *(const bf16x8*)&vls[pr * 32 + (l & 31)][s * 16 + (l >> 5) * 8];
    *(bf16x8*)(kvF + ob + 8192 + (size_t)g * 8) = vv8;
  }
}

// ---- main: 4 waves x 32 q-rows = 128 rows/block; tile staged ONCE per block
// into LDS (frag-major, linear, conflict-free), read by all 4 waves.
// 3 LDS buffers (72KB) -> 2 blocks/CU (2 waves/SIMD); counted-vmcnt pipeline.
__global__ __launch_bounds__(256, 2) void attn_causal_fwd(
    const float* __restrict__ q, const short* __restrict__ kvF,
    float* __restrict__ out) {
  __shared__ short lds3[3][12288];  // 3 x 24KB tile buffers

  const int tid = threadIdx.x;
  const int wave = tid >> 6;
  const int lane = tid & 63;
  const int q31 = lane & 31;
  const int h5 = lane >> 5;

  // 512 blocks: c=lid&255 -> (head = c&31, j = c>>5); hi=lid>>8: qb = hi? j:15-j.
  // Blocks c and c+256 (same CU slot pairing) get qb j and 15-j -> 34 tiles/CU.
  // XCD = lid&7 = head&7 -> 4 heads/XCD (3MB frag data fits 4MB L2). Heavy first.
  const int lid = (int)blockIdx.x;
  const int c = lid & 255;
  const int head = c & 31;
  const int j = c >> 5;
  const int qb = (lid >> 8) ? j : 15 - j;
  const int qbase = qb * 128;
  const size_t base = (size_t)head * SQ * DH;
  const int qrow_w = qbase + wave * 32;  // wave's 32 q-rows
  const short* kvB = kvF + (size_t)head * 32 * 12288;

  // ---- Q fragments scaled by log2e, bf16 hi/lo split
  bf16x8 qh[4], ql[4];
#pragma unroll
  for (int ks = 0; ks < 4; ++ks) {
    const float* qp = q + base + (size_t)(qrow_w + q31) * DH + ks * 16 + h5 * 8;
    float4 a = *(const float4*)qp;
    float4 b = *(const float4*)(qp + 4);
    a.x *= LOG2E; a.y *= LOG2E; a.z *= LOG2E; a.w *= LOG2E;
    b.x *= LOG2E; b.y *= LOG2E; b.z *= LOG2E; b.w *= LOG2E;
    unsigned h0 = cvtpk(a.x, a.y), h1 = cvtpk(a.z, a.w);
    unsigned h2 = cvtpk(b.x, b.y), h3 = cvtpk(b.z, b.w);
    unsigned l0 = cvtpk(a.x - uasf(h0 << 16), a.y - uasf(h0 & 0xffff0000u));
    unsigned l1 = cvtpk(a.z - uasf(h1 << 16), a.w - uasf(h1 & 0xffff0000u));
    unsigned l2 = cvtpk(b.x - uasf(h2 << 16), b.y - uasf(h2 & 0xffff0000u));
    unsigned l3 = cvtpk(b.z - uasf(h3 << 16), b.w - uasf(h3 & 0xffff0000u));
    AFrag fh; fh.u[0] = h0; fh.u[1] = h1; fh.u[2] = h2; fh.u[3] = h3; qh[ks] = fh.v;
    AFrag fl; fl.u[0] = l0; fl.u[1] = l1; fl.u[2] = l2; fl.u[3] = l3; ql[ks] = fl.v;
  }

  // ---- staging: 6 x gll16 per thread per tile; dst wave-uniform + lane*16
#define STAGE(tt, nb)                                                        \
  do {                                                                       \
    const char* srcb = (const char*)(kvB + (size_t)(tt)*12288);              \
    _Pragma("unroll") for (int i = 0; i < 6; ++i) {                          \
      gll16(srcb + i * 4096 + wave * 1024 + lane * 16,                       \
            &lds3[nb][i * 2048 + wave * 512]);                               \
    }                                                                        \
  } while (0)

  const int ntiles = qb * 2 + 2;
  STAGE(0, 0);
  if (ntiles > 1) STAGE(1, 1);

  f32x16 o0, o1;
#pragma unroll
  for (int r = 0; r < 16; ++r) { o0[r] = 0.f; o1[r] = 0.f; }
  float m_run = -1e30f, l_run = 0.f;

  for (int t = 0; t < ntiles; ++t) {
    const int kv0 = t * 64;
    // entry: stage(t) + stage(t+1) outstanding; wait stage(t) landed
    if (t + 1 < ntiles) {
      asm volatile("s_waitcnt vmcnt(6)" ::: "memory");
    } else {
      asm volatile("s_waitcnt vmcnt(0)" ::: "memory");
    }
    __builtin_amdgcn_sched_barrier(0);
    __builtin_amdgcn_s_barrier();
    __builtin_amdgcn_sched_barrier(0);
    if (t + 2 < ntiles) STAGE(t + 2, (t + 2) % 3);  // lands in buf of t-1

    const short* B = &lds3[t % 3][0];

    if (kv0 <= qrow_w + 31) {  // wave-uniform activity
      const int nk = (kv0 + 32 <= qrow_w + 31) ? 2 : 1;

      // ---- operand reads: ds_read_b128, base + lane*16 (conflict-free)
      bf16x8 ah[2][4], al[2][4], bv[4][2];
#pragma unroll
      for (int kt = 0; kt < 2; ++kt) {
        if (kt < nk) {
#pragma unroll
          for (int ks = 0; ks < 4; ++ks) {
            ah[kt][ks] = *(const bf16x8*)(B + (kt * 4 + ks) * 512 + lane * 8);
            al[kt][ks] = *(const bf16x8*)(B + 4096 + (kt * 4 + ks) * 512 + lane * 8);
          }
        }
      }
#pragma unroll
      for (int s = 0; s < 4; ++s) {
        if ((s >> 1) < nk) {
#pragma unroll
          for (int pr = 0; pr < 2; ++pr)
            bv[s][pr] = *(const bf16x8*)(B + 8192 + (s * 2 + pr) * 512 + lane * 8);
        }
      }

      // ---- S^T = K·Q (swapped): lane-local P rows; 3-term hi/lo
      f32x16 sa[2];
      __builtin_amdgcn_s_setprio(1);
#pragma unroll
      for (int kt = 0; kt < 2; ++kt) {
        if (kt < nk) {
#pragma unroll
          for (int r = 0; r < 16; ++r) sa[kt][r] = 0.f;
#pragma unroll
          for (int ks = 0; ks < 4; ++ks) {
            sa[kt] = __builtin_amdgcn_mfma_f32_32x32x16_bf16(ah[kt][ks], qh[ks], sa[kt], 0, 0, 0);
            sa[kt] = __builtin_amdgcn_mfma_f32_32x32x16_bf16(al[kt][ks], qh[ks], sa[kt], 0, 0, 0);
            sa[kt] = __builtin_amdgcn_mfma_f32_32x32x16_bf16(ah[kt][ks], ql[ks], sa[kt], 0, 0, 0);
          }
        }
      }
      __builtin_amdgcn_s_setprio(0);

      // ---- causal mask on diagonal halves only
#pragma unroll
      for (int kt = 0; kt < 2; ++kt) {
        if (kt < nk && !(kv0 + kt * 32 + 31 <= qrow_w)) {
          const int qg = qrow_w + q31;
#pragma unroll
          for (int r = 0; r < 16; ++r) {
            int kvv = kv0 + kt * 32 + (r & 3) + 8 * (r >> 2) + 4 * h5;
            sa[kt][r] = (kvv <= qg) ? sa[kt][r] : -1e30f;
          }
        }
      }

      // ---- online softmax (log2 domain), defer-rescale THR=8
      float m16 = -1e30f;
#pragma unroll
      for (int kt = 0; kt < 2; ++kt)
        if (kt < nk)
#pragma unroll
          for (int r = 0; r < 16; ++r) m16 = fmaxf(m16, sa[kt][r]);
      float mm = fmaxf(m16, __shfl_xor(m16, 32));
      if (!__all(mm - m_run <= 8.0f)) {
        float mnew = fmaxf(m_run, mm);
        float sc = exp2asm(m_run - mnew);
        l_run *= sc;
        m_run = mnew;
#pragma unroll
        for (int r = 0; r < 16; ++r) {
          float s_r = __shfl(sc, (r & 3) + 8 * (r >> 2) + 4 * h5);
          o0[r] *= s_r;
          o1[r] *= s_r;
        }
      }
      float rs = 0.f;
      unsigned cpk[2][8];
#pragma unroll
      for (int kt = 0; kt < 2; ++kt) {
        if (kt < nk) {
#pragma unroll
          for (int r = 0; r < 16; ++r) {
            float e = exp2asm(sa[kt][r] - m_run);
            sa[kt][r] = e;
            rs += e;
          }
#pragma unroll
          for (int i = 0; i < 8; ++i)
            cpk[kt][i] = cvtpk(sa[kt][2 * i], sa[kt][2 * i + 1]);
        }
      }
      rs += __shfl_xor(rs, 32);
      l_run += rs;

      // ---- O += P·V : A-frags in-register via half-swap (T12)
      __builtin_amdgcn_s_setprio(1);
#pragma unroll
      for (int s = 0; s < 4; ++s) {
        if ((s >> 1) < nk) {
          const int kt = s >> 1, s1 = s & 1;
          unsigned P0 = cpk[kt][s1 * 4 + 0], P1 = cpk[kt][s1 * 4 + 1];
          unsigned Q0 = cpk[kt][s1 * 4 + 2], Q1 = cpk[kt][s1 * 4 + 3];
          unsigned X0 = h5 ? Q0 : P0, Z0 = h5 ? P0 : Q0;
          unsigned X1 = h5 ? Q1 : P1, Z1 = h5 ? P1 : Q1;
          unsigned c0 = (unsigned)__shfl_xor((int)Z0, 32);
          unsigned c1 = (unsigned)__shfl_xor((int)Z1, 32);
          AFrag af;
          af.u[0] = h5 ? c0 : X0;
          af.u[1] = h5 ? c1 : X1;
          af.u[2] = h5 ? X0 : c0;
          af.u[3] = h5 ? X1 : c1;
          o0 = __builtin_amdgcn_mfma_f32_32x32x16_bf16(af.v, bv[s][0], o0, 0, 0, 0);
          o1 = __builtin_amdgcn_mfma_f32_32x32x16_bf16(af.v, bv[s][1], o1, 0, 0, 0);
        }
      }
      __builtin_amdgcn_s_setprio(0);
    }
  }

  // ---- epilogue: O / l
  float inv = 1.0f / l_run;
#pragma unroll
  for (int r = 0; r < 16; ++r) {
    int qr = (r & 3) + 8 * (r >> 2) + 4 * h5;
    float ss = __shfl(inv, qr);
    float* op = out + base + (size_t)(qrow_w + qr) * DH + q31;
    op[0] = o0[r] * ss;
    op[32] = o1[r] * ss;
  }
}

extern "C" void kernel_launch(void* const* d_in, const int* in_sizes, int n_in,
                              void* d_out, int out_size, void* d_ws, size_t ws_size,
                              hipStream_t stream) {
  const float* q = (const float*)d_in[0];
  const float* k = (const float*)d_in[1];
  const float* v = (const float*)d_in[2];
  // d_in[3] (mask) is tril(ones) by construction -> applied analytically.
  float* out = (float*)d_out;
  short* kvF = (short*)d_ws;  // 32 heads x 32 tiles x 24KB = 24 MB

  hipLaunchKernelGGL(prep_kv, dim3(SQ / 64, NB * NH), dim3(256), 0, stream,
                     k, v, kvF);
  hipLaunchKernelGGL(attn_causal_fwd, dim3(512), dim3(256), 0, stream,
                     q, kvF, out);
}

// Round 7
// 67.632 us; speedup vs baseline: 1.8653x; 1.0308x over previous
//
#include <hip/hip_runtime.h>
#include <hip/hip_bf16.h>

#define NB 2
#define NH 16
#define SQ 2048
#define DH 64
#define LOG2E 1.44269504088896340736f

typedef _Float16 f16x8 __attribute__((ext_vector_type(8)));
typedef float f32x16 __attribute__((ext_vector_type(16)));
typedef unsigned u32x2 __attribute__((ext_vector_type(2)));

__device__ __forceinline__ float exp2asm(float x) {  // 2^x
  float r;
  asm("v_exp_f32 %0, %1" : "=v"(r) : "v"(x));
  return r;
}
__device__ __forceinline__ unsigned pkrtz(float a, float b) {  // 2xfp16 pack
  unsigned r;
  asm("v_cvt_pkrtz_f16_f32 %0, %1, %2" : "=v"(r) : "v"(a), "v"(b));
  return r;
}
__device__ __forceinline__ void gll16(const void* g, void* l) {
  __builtin_amdgcn_global_load_lds(
      (const __attribute__((address_space(1))) void*)g,
      (__attribute__((address_space(3))) void*)l, 16, 0, 0);
}

union AFrag { unsigned u[4]; f16x8 v; };
union H4 { _Float16 h[4]; u32x2 u2; };
union HS { _Float16 h; short s; };

// ---- pre-pass: per (head, 64-kv tile) a 16KB FRAG-MAJOR chunk:
//   [K fp16 8KB | V^T fp16 8KB], each = 8 granules of 1KB,
//   granule = 64 lanes x 16B = exactly one wave MFMA operand.
//   K granule (kt,ks): lane l <- K[kt*32+(l&31)][ks*16+(l>>5)*8 +0..7]
//   V granule (s,pr) : lane l <- V^T[pr*32+(l&31)][s*16+(l>>5)*8 +0..7]
__global__ __launch_bounds__(256) void prep_kv(
    const float* __restrict__ k, const float* __restrict__ v,
    short* __restrict__ kvF) {
  __shared__ short kls[64][72];  // K fp16 bits
  __shared__ short vls[64][72];  // V^T fp16 bits: vls[d][kv]
  const int tid = threadIdx.x;
  const int t = blockIdx.x;   // kv tile (64 rows)
  const int bh = blockIdx.y;
  const size_t inbase = ((size_t)bh * SQ + t * 64) * DH;
#pragma unroll
  for (int i = 0; i < 4; ++i) {
    int idx = i * 256 + tid;
    int row = idx >> 4;
    int c4 = (idx & 15) << 2;
    float4 kk = *(const float4*)(k + inbase + row * DH + c4);
    H4 p;
    p.h[0] = (_Float16)kk.x; p.h[1] = (_Float16)kk.y;
    p.h[2] = (_Float16)kk.z; p.h[3] = (_Float16)kk.w;
    *(u32x2*)&kls[row][c4] = p.u2;
    float4 vv = *(const float4*)(v + inbase + row * DH + c4);
    HS a0, a1, a2, a3;
    a0.h = (_Float16)vv.x; a1.h = (_Float16)vv.y;
    a2.h = (_Float16)vv.z; a3.h = (_Float16)vv.w;
    vls[c4 + 0][row] = a0.s;
    vls[c4 + 1][row] = a1.s;
    vls[c4 + 2][row] = a2.s;
    vls[c4 + 3][row] = a3.s;
  }
  __syncthreads();
  const size_t ob = ((size_t)bh * 32 + t) * 8192;  // shorts (16KB chunks)
#pragma unroll
  for (int half = 0; half < 2; ++half) {
    int g = half * 256 + tid;  // 0..511
    int kt = g >> 8, ks = (g >> 6) & 3, l = g & 63;
    f16x8 kv8 = *(const f16x8*)&kls[kt * 32 + (l & 31)][ks * 16 + (l >> 5) * 8];
    *(f16x8*)(kvF + ob + (size_t)g * 8) = kv8;
    int s = (g >> 7) & 3, pr = (g >> 6) & 1;
    f16x8 vv8 = *(const f16x8*)&vls[pr * 32 + (l & 31)][s * 16 + (l >> 5) * 8];
    *(f16x8*)(kvF + ob + 4096 + (size_t)g * 8) = vv8;
  }
}

// ---- main: 4 waves x 32 q-rows; 16KB tile staged once per block into LDS,
// 4 buffers (64KB) -> 2 blocks/CU; counted-vmcnt pipeline (depth 3).
__global__ __launch_bounds__(256, 2) void attn_causal_fwd(
    const float* __restrict__ q, const short* __restrict__ kvF,
    float* __restrict__ out) {
  __shared__ short lds4[4][8192];  // 4 x 16KB tile buffers

  const int tid = threadIdx.x;
  const int wave = tid >> 6;
  const int lane = tid & 63;
  const int q31 = lane & 31;
  const int h5 = lane >> 5;

  // 512 blocks; CU pairs qb j with 15-j -> constant 36 block-tiles per CU
  // (optimal under the movement-bound model). XCD = head%8 -> 4 heads/XCD,
  // fp16 frag data 2MB fits 4MB L2. Heavy first.
  const int lid = (int)blockIdx.x;
  const int c = lid & 255;
  const int head = c & 31;
  const int j = c >> 5;
  const int qb = (lid >> 8) ? j : 15 - j;
  const int qbase = qb * 128;
  const size_t base = (size_t)head * SQ * DH;
  const int qrow_w = qbase + wave * 32;  // wave's 32 q-rows
  const short* kvB = kvF + (size_t)head * 32 * 8192;

  // ---- Q fragments scaled by log2e, fp16 hi/lo split (2-term QK)
  f16x8 qh[4], ql[4];
#pragma unroll
  for (int ks = 0; ks < 4; ++ks) {
    const float* qp = q + base + (size_t)(qrow_w + q31) * DH + ks * 16 + h5 * 8;
    float4 a = *(const float4*)qp;
    float4 b = *(const float4*)(qp + 4);
    float f[8] = {a.x, a.y, a.z, a.w, b.x, b.y, b.z, b.w};
    union { _Float16 h[8]; f16x8 v; } fh, fl;
#pragma unroll
    for (int e = 0; e < 8; ++e) {
      float qs = f[e] * LOG2E;
      _Float16 hh = (_Float16)qs;
      fh.h[e] = hh;
      fl.h[e] = (_Float16)(qs - (float)hh);
    }
    qh[ks] = fh.v;
    ql[ks] = fl.v;
  }

  // ---- staging: 4 x gll16 per thread per tile; dst wave-uniform + lane*16
#define STAGE(tt, nb)                                                        \
  do {                                                                       \
    const char* srcb = (const char*)(kvB + (size_t)(tt)*8192);               \
    _Pragma("unroll") for (int i = 0; i < 4; ++i) {                          \
      gll16(srcb + i * 4096 + wave * 1024 + lane * 16,                       \
            &lds4[nb][i * 2048 + wave * 512]);                               \
    }                                                                        \
  } while (0)

  const int ntiles = qb * 2 + 2;
  STAGE(0, 0);
  if (ntiles > 1) STAGE(1, 1);
  if (ntiles > 2) STAGE(2, 2);

  f32x16 o0, o1;
#pragma unroll
  for (int r = 0; r < 16; ++r) { o0[r] = 0.f; o1[r] = 0.f; }
  float m_run = -1e30f, l_run = 0.f;

  for (int t = 0; t < ntiles; ++t) {
    const int kv0 = t * 64;
    const int rem = ntiles - 1 - t;  // stages still wanted in flight
    if (rem >= 2) {
      asm volatile("s_waitcnt vmcnt(8)" ::: "memory");
    } else if (rem == 1) {
      asm volatile("s_waitcnt vmcnt(4)" ::: "memory");
    } else {
      asm volatile("s_waitcnt vmcnt(0)" ::: "memory");
    }
    __builtin_amdgcn_sched_barrier(0);
    __builtin_amdgcn_s_barrier();
    __builtin_amdgcn_sched_barrier(0);
    if (t + 3 < ntiles) STAGE(t + 3, (t + 3) & 3);  // overwrites buf of t-1

    const short* B = &lds4[t & 3][0];

    if (kv0 <= qrow_w + 31) {  // wave-uniform activity
      const int nk = (kv0 + 32 <= qrow_w + 31) ? 2 : 1;

      // ---- operand reads: ds_read_b128, base + lane*16 (conflict-free)
      f16x8 kf[2][4], bv[4][2];
#pragma unroll
      for (int kt = 0; kt < 2; ++kt)
        if (kt < nk)
#pragma unroll
          for (int ks = 0; ks < 4; ++ks)
            kf[kt][ks] = *(const f16x8*)(B + (kt * 4 + ks) * 512 + lane * 8);
#pragma unroll
      for (int s = 0; s < 4; ++s)
        if ((s >> 1) < nk)
#pragma unroll
          for (int pr = 0; pr < 2; ++pr)
            bv[s][pr] = *(const f16x8*)(B + 4096 + (s * 2 + pr) * 512 + lane * 8);

      // ---- S^T = K·Q (swapped): lane-local P rows; 2-term fp16
      f32x16 sa[2];
      __builtin_amdgcn_s_setprio(1);
#pragma unroll
      for (int kt = 0; kt < 2; ++kt) {
        if (kt < nk) {
#pragma unroll
          for (int r = 0; r < 16; ++r) sa[kt][r] = 0.f;
#pragma unroll
          for (int ks = 0; ks < 4; ++ks) {
            sa[kt] = __builtin_amdgcn_mfma_f32_32x32x16_f16(kf[kt][ks], qh[ks], sa[kt], 0, 0, 0);
            sa[kt] = __builtin_amdgcn_mfma_f32_32x32x16_f16(kf[kt][ks], ql[ks], sa[kt], 0, 0, 0);
          }
        }
      }
      __builtin_amdgcn_s_setprio(0);

      // ---- causal mask on diagonal halves only
#pragma unroll
      for (int kt = 0; kt < 2; ++kt) {
        if (kt < nk && !(kv0 + kt * 32 + 31 <= qrow_w)) {
          const int qg = qrow_w + q31;
#pragma unroll
          for (int r = 0; r < 16; ++r) {
            int kvv = kv0 + kt * 32 + (r & 3) + 8 * (r >> 2) + 4 * h5;
            sa[kt][r] = (kvv <= qg) ? sa[kt][r] : -1e30f;
          }
        }
      }

      // ---- online softmax (log2 domain), tree reductions, defer-rescale
      float mv[16];
#pragma unroll
      for (int r = 0; r < 16; ++r)
        mv[r] = (nk == 2) ? fmaxf(sa[0][r], sa[1][r]) : sa[0][r];
#pragma unroll
      for (int st = 8; st > 0; st >>= 1)
#pragma unroll
        for (int i = 0; i < 8; ++i)
          if (i < st) mv[i] = fmaxf(mv[i], mv[i + st]);
      float mm = fmaxf(mv[0], __shfl_xor(mv[0], 32));
      if (!__all(mm - m_run <= 8.0f)) {
        float mnew = fmaxf(m_run, mm);
        float sc = exp2asm(m_run - mnew);
        l_run *= sc;
        m_run = mnew;
#pragma unroll
        for (int r = 0; r < 16; ++r) {
          float s_r = __shfl(sc, (r & 3) + 8 * (r >> 2) + 4 * h5);
          o0[r] *= s_r;
          o1[r] *= s_r;
        }
      }
      unsigned cpk[2][8];
      float sv[16];
#pragma unroll
      for (int kt = 0; kt < 2; ++kt)
        if (kt < nk)
#pragma unroll
          for (int r = 0; r < 16; ++r) sa[kt][r] = exp2asm(sa[kt][r] - m_run);
#pragma unroll
      for (int r = 0; r < 16; ++r)
        sv[r] = (nk == 2) ? sa[0][r] + sa[1][r] : sa[0][r];
#pragma unroll
      for (int st = 8; st > 0; st >>= 1)
#pragma unroll
        for (int i = 0; i < 8; ++i)
          if (i < st) sv[i] += sv[i + st];
      l_run += sv[0] + __shfl_xor(sv[0], 32);
#pragma unroll
      for (int kt = 0; kt < 2; ++kt)
        if (kt < nk)
#pragma unroll
          for (int i = 0; i < 8; ++i)
            cpk[kt][i] = pkrtz(sa[kt][2 * i], sa[kt][2 * i + 1]);

      // ---- O += P·V : A-frags in-register via half-swap (T12)
      __builtin_amdgcn_s_setprio(1);
#pragma unroll
      for (int s = 0; s < 4; ++s) {
        if ((s >> 1) < nk) {
          const int kt = s >> 1, s1 = s & 1;
          unsigned P0 = cpk[kt][s1 * 4 + 0], P1 = cpk[kt][s1 * 4 + 1];
          unsigned Q0 = cpk[kt][s1 * 4 + 2], Q1 = cpk[kt][s1 * 4 + 3];
          unsigned X0 = h5 ? Q0 : P0, Z0 = h5 ? P0 : Q0;
          unsigned X1 = h5 ? Q1 : P1, Z1 = h5 ? P1 : Q1;
          unsigned c0 = (unsigned)__shfl_xor((int)Z0, 32);
          unsigned c1 = (unsigned)__shfl_xor((int)Z1, 32);
          AFrag af;
          af.u[0] = h5 ? c0 : X0;
          af.u[1] = h5 ? c1 : X1;
          af.u[2] = h5 ? X0 : c0;
          af.u[3] = h5 ? X1 : c1;
          o0 = __builtin_amdgcn_mfma_f32_32x32x16_f16(af.v, bv[s][0], o0, 0, 0, 0);
          o1 = __builtin_amdgcn_mfma_f32_32x32x16_f16(af.v, bv[s][1], o1, 0, 0, 0);
        }
      }
      __builtin_amdgcn_s_setprio(0);
    }
  }

  // ---- epilogue: O / l
  float inv = 1.0f / l_run;
#pragma unroll
  for (int r = 0; r < 16; ++r) {
    int qr = (r & 3) + 8 * (r >> 2) + 4 * h5;
    float ss = __shfl(inv, qr);
    float* op = out + base + (size_t)(qrow_w + qr) * DH + q31;
    op[0] = o0[r] * ss;
    op[32] = o1[r] * ss;
  }
}

extern "C" void kernel_launch(void* const* d_in, const int* in_sizes, int n_in,
                              void* d_out, int out_size, void* d_ws, size_t ws_size,
                              hipStream_t stream) {
  const float* q = (const float*)d_in[0];
  const float* k = (const float*)d_in[1];
  const float* v = (const float*)d_in[2];
  // d_in[3] (mask) is tril(ones) by construction -> applied analytically.
  float* out = (float*)d_out;
  short* kvF = (short*)d_ws;  // 32 heads x 32 tiles x 16KB = 16 MB

  hipLaunchKernelGGL(prep_kv, dim3(SQ / 64, NB * NH), dim3(256), 0, stream,
                     k, v, kvF);
  hipLaunchKernelGGL(attn_causal_fwd, dim3(512), dim3(256), 0, stream,
                     q, kvF, out);
}